// Round 2
// baseline (366.315 us; speedup 1.0000x reference)
//
#include <hip/hip_runtime.h>

// Problem constants (reference: DIM=64, WIRES=3, INDEX=1, BATCH=128)
#define DIMQ   64
#define NCOLS  8192            // right * batch = 64*128
#define SLAB   (DIMQ * NCOLS)  // per-a complex elements = 524288
#define NA     64              // left = dim^index
#define DB     (NA * SLAB)     // D*B = 33554432

typedef __attribute__((ext_vector_type(8))) __bf16 bf16x8;
typedef __attribute__((ext_vector_type(8))) unsigned short us8;
typedef __attribute__((ext_vector_type(4))) float f32x4;

__device__ __forceinline__ unsigned short f2bf(float f) {
    unsigned u = __builtin_bit_cast(unsigned, f);
    unsigned r = u + 0x7fffu + ((u >> 16) & 1u);   // RNE to bf16
    return (unsigned short)(r >> 16);
}

// Load M A-fragments (A[m=l15][k=q*8+j]) for all 4 i-tiles / 2 k-blocks.
__device__ __forceinline__ void load_M_frags(
    const float* __restrict__ Mr, const float* __restrict__ Mi,
    int l15, int q, bf16x8 fMr[4][2], bf16x8 fMi[4][2])
{
#pragma unroll
    for (int it = 0; it < 4; ++it) {
#pragma unroll
        for (int kb = 0; kb < 2; ++kb) {
            const int row = it * 16 + l15;
            const int col = kb * 32 + q * 8;
            const float* pr = Mr + row * DIMQ + col;
            const float* pi = Mi + row * DIMQ + col;
            us8 hr, hi;
#pragma unroll
            for (int j = 0; j < 8; ++j) {
                hr[j] = f2bf(pr[j]);
                hi[j] = f2bf(pi[j]);
            }
            fMr[it][kb] = __builtin_bit_cast(bf16x8, hr);
            fMi[it][kb] = __builtin_bit_cast(bf16x8, hi);
        }
    }
}

// ---- Variant A: output = Re(y) only, out_size = D*B float32 ----
__global__ __launch_bounds__(64, 2) void gate_real_kernel(
    const float* __restrict__ Mr, const float* __restrict__ Mi,
    const float* __restrict__ Xr, const float* __restrict__ Xi,
    float* __restrict__ Out)
{
    const int lane = threadIdx.x;
    const int l15  = lane & 15;
    const int q    = lane >> 4;

    bf16x8 fMr[4][2], fMi[4][2];
    load_M_frags(Mr, Mi, l15, q, fMr, fMi);

    const int bid = blockIdx.x;
    const int a   = bid >> 6;
    const int nch = bid & 63;
    const size_t baseA = (size_t)a * SLAB;

    for (int tt = 0; tt < 8; ++tt) {
        const int n0 = nch * 128 + tt * 16;
        f32x4 accR[4] = {f32x4{0,0,0,0}, f32x4{0,0,0,0}, f32x4{0,0,0,0}, f32x4{0,0,0,0}};

#pragma unroll
        for (int kb = 0; kb < 2; ++kb) {
            const int krow = kb * 32 + q * 8;
            const float* pr = Xr + baseA + (size_t)krow * NCOLS + n0 + l15;
            const float* pi = Xi + baseA + (size_t)krow * NCOLS + n0 + l15;
            float fr[8], fi[8];
#pragma unroll
            for (int j = 0; j < 8; ++j) {
                fr[j] = pr[(size_t)j * NCOLS];
                fi[j] = pi[(size_t)j * NCOLS];
            }
            us8 hr, hni;
#pragma unroll
            for (int j = 0; j < 8; ++j) {
                hr[j]  = f2bf(fr[j]);
                hni[j] = (unsigned short)(f2bf(fi[j]) ^ 0x8000u);   // -Xi
            }
            const bf16x8 bXr  = __builtin_bit_cast(bf16x8, hr);
            const bf16x8 bXni = __builtin_bit_cast(bf16x8, hni);

#pragma unroll
            for (int it = 0; it < 4; ++it) {
                accR[it] = __builtin_amdgcn_mfma_f32_16x16x32_bf16(fMr[it][kb], bXr,  accR[it], 0, 0, 0);
                accR[it] = __builtin_amdgcn_mfma_f32_16x16x32_bf16(fMi[it][kb], bXni, accR[it], 0, 0, 0);
            }
        }

        // C/D layout: col = l15, row = q*4 + r
#pragma unroll
        for (int it = 0; it < 4; ++it) {
#pragma unroll
            for (int r = 0; r < 4; ++r) {
                const int i = it * 16 + q * 4 + r;
                Out[baseA + (size_t)i * NCOLS + n0 + l15] = accR[it][r];
            }
        }
    }
}

// ---- Variant B (fallback): interleaved complex64 view, out_size = 2*D*B ----
__global__ __launch_bounds__(64, 2) void gate_cplx_kernel(
    const float* __restrict__ Mr, const float* __restrict__ Mi,
    const float* __restrict__ Xr, const float* __restrict__ Xi,
    float* __restrict__ Out)
{
    const int lane = threadIdx.x;
    const int l15  = lane & 15;
    const int q    = lane >> 4;

    bf16x8 fMr[4][2], fMi[4][2];
    load_M_frags(Mr, Mi, l15, q, fMr, fMi);

    const int bid = blockIdx.x;
    const int a   = bid >> 6;
    const int nch = bid & 63;
    const size_t baseA = (size_t)a * SLAB;

    for (int tt = 0; tt < 8; ++tt) {
        const int n0 = nch * 128 + tt * 16;
        f32x4 accR[4] = {f32x4{0,0,0,0}, f32x4{0,0,0,0}, f32x4{0,0,0,0}, f32x4{0,0,0,0}};
        f32x4 accI[4] = {f32x4{0,0,0,0}, f32x4{0,0,0,0}, f32x4{0,0,0,0}, f32x4{0,0,0,0}};

#pragma unroll
        for (int kb = 0; kb < 2; ++kb) {
            const int krow = kb * 32 + q * 8;
            const float* pr = Xr + baseA + (size_t)krow * NCOLS + n0 + l15;
            const float* pi = Xi + baseA + (size_t)krow * NCOLS + n0 + l15;
            float fr[8], fi[8];
#pragma unroll
            for (int j = 0; j < 8; ++j) {
                fr[j] = pr[(size_t)j * NCOLS];
                fi[j] = pi[(size_t)j * NCOLS];
            }
            us8 hr, hi, hni;
#pragma unroll
            for (int j = 0; j < 8; ++j) {
                hr[j] = f2bf(fr[j]);
                const unsigned short t = f2bf(fi[j]);
                hi[j]  = t;
                hni[j] = (unsigned short)(t ^ 0x8000u);
            }
            const bf16x8 bXr  = __builtin_bit_cast(bf16x8, hr);
            const bf16x8 bXi  = __builtin_bit_cast(bf16x8, hi);
            const bf16x8 bXni = __builtin_bit_cast(bf16x8, hni);

#pragma unroll
            for (int it = 0; it < 4; ++it) {
                accR[it] = __builtin_amdgcn_mfma_f32_16x16x32_bf16(fMr[it][kb], bXr,  accR[it], 0, 0, 0);
                accR[it] = __builtin_amdgcn_mfma_f32_16x16x32_bf16(fMi[it][kb], bXni, accR[it], 0, 0, 0);
                accI[it] = __builtin_amdgcn_mfma_f32_16x16x32_bf16(fMr[it][kb], bXi,  accI[it], 0, 0, 0);
                accI[it] = __builtin_amdgcn_mfma_f32_16x16x32_bf16(fMi[it][kb], bXr,  accI[it], 0, 0, 0);
            }
        }

#pragma unroll
        for (int it = 0; it < 4; ++it) {
#pragma unroll
            for (int r = 0; r < 4; ++r) {
                const int i = it * 16 + q * 4 + r;
                const size_t cidx = baseA + (size_t)i * NCOLS + n0 + l15;
                float2 v;
                v.x = accR[it][r];
                v.y = accI[it][r];
                reinterpret_cast<float2*>(Out)[cidx] = v;
            }
        }
    }
}

extern "C" void kernel_launch(void* const* d_in, const int* in_sizes, int n_in,
                              void* d_out, int out_size, void* d_ws, size_t ws_size,
                              hipStream_t stream) {
    const float* Mr = (const float*)d_in[0];
    const float* Mi = (const float*)d_in[1];
    const float* Xr = (const float*)d_in[2];
    const float* Xi = (const float*)d_in[3];
    float* Out = (float*)d_out;

    dim3 grid(NA * 64);   // 64 a-slabs * 64 column-chunks (128 cols each)
    dim3 block(64);
    if (out_size >= 2 * DB) {
        gate_cplx_kernel<<<grid, block, 0, stream>>>(Mr, Mi, Xr, Xi, Out);
    } else {
        gate_real_kernel<<<grid, block, 0, stream>>>(Mr, Mi, Xr, Xi, Out);
    }
}